// Round 1
// baseline (664.007 us; speedup 1.0000x reference)
//
#include <hip/hip_runtime.h>
#include <hip/hip_bf16.h>

typedef __attribute__((ext_vector_type(8))) short short8;
typedef __attribute__((ext_vector_type(4))) float floatx4;

#define M_DIM 8192
#define N_DIM 4096
#define K_DIM 4096
#define BM 128
#define BN 128
#define BK 64

__device__ __constant__ float NF4_TAB[16] = {
    -1.0f, -0.6961928009986877f, -0.5250730514526367f, -0.39491748809814453f,
    -0.28444138169288635f, -0.18477343022823334f, -0.09105003625154495f, 0.0f,
    0.07958029955625534f, 0.16093020141124725f, 0.24611230194568634f,
    0.33791524171829224f, 0.44070982933044434f, 0.5626170039176941f,
    0.7229568362236023f, 1.0f};

// laT[k*16+r] = lora_A[r*K + k]  (65536 elements)
__global__ void transpose_la_kernel(const float* __restrict__ la,
                                    float* __restrict__ laT) {
    int g = blockIdx.x * blockDim.x + threadIdx.x;
    int r = g & 15, k = g >> 4;
    laT[g] = la[r * K_DIM + k];
}

// W_eff[n][k] = NF4[code]*scale + 2*sum_r loraB[n][r]*loraA[r][k], as bf16
__global__ void dequant_lora_kernel(const int* __restrict__ codes,
                                    const float* __restrict__ scales,
                                    const float* __restrict__ laT,
                                    const float* __restrict__ loraB,
                                    short8* __restrict__ W) {
    int g = blockIdx.x * blockDim.x + threadIdx.x;  // one thread per 8 k-elems
    int n = g >> 9;          // K/8 = 512 groups per row
    int kb = g & 511;
    int k0 = kb << 3;
    float scale = scales[(n << 6) + (k0 >> 6)];
    const int4* cp = (const int4*)(codes + (size_t)n * K_DIM + k0);
    int4 c0 = cp[0], c1 = cp[1];
    int cs[8] = {c0.x, c0.y, c0.z, c0.w, c1.x, c1.y, c1.z, c1.w};
    const float4* lb = (const float4*)(loraB + (n << 4));
    float4 b0 = lb[0], b1 = lb[1], b2 = lb[2], b3 = lb[3];
    union { short8 v; __hip_bfloat16 h[8]; } u;
#pragma unroll
    for (int j = 0; j < 8; j++) {
        const float4* la = (const float4*)(laT + (size_t)(k0 + j) * 16);
        float4 a0 = la[0], a1 = la[1], a2 = la[2], a3 = la[3];
        float dot = b0.x * a0.x + b0.y * a0.y + b0.z * a0.z + b0.w * a0.w +
                    b1.x * a1.x + b1.y * a1.y + b1.z * a1.z + b1.w * a1.w +
                    b2.x * a2.x + b2.y * a2.y + b2.z * a2.z + b2.w * a2.w +
                    b3.x * a3.x + b3.y * a3.y + b3.z * a3.z + b3.w * a3.w;
        float w = NF4_TAB[cs[j]] * scale + 2.0f * dot;
        u.h[j] = __float2bfloat16(w);
    }
    W[g] = u.v;
}

// fp32 -> bf16 cast, 8 elements per thread
__global__ void cast_x_kernel(const float* __restrict__ x,
                              short8* __restrict__ xb) {
    int g = blockIdx.x * blockDim.x + threadIdx.x;
    const float4* xp = (const float4*)(x + (size_t)g * 8);
    float4 v0 = xp[0], v1 = xp[1];
    union { short8 v; __hip_bfloat16 h[8]; } u;
    u.h[0] = __float2bfloat16(v0.x);
    u.h[1] = __float2bfloat16(v0.y);
    u.h[2] = __float2bfloat16(v0.z);
    u.h[3] = __float2bfloat16(v0.w);
    u.h[4] = __float2bfloat16(v1.x);
    u.h[5] = __float2bfloat16(v1.y);
    u.h[6] = __float2bfloat16(v1.z);
    u.h[7] = __float2bfloat16(v1.w);
    xb[g] = u.v;
}

#define GL2LDS(gsrc, ldst)                                                   \
    __builtin_amdgcn_global_load_lds(                                        \
        (const __attribute__((address_space(1))) void*)(gsrc),               \
        (__attribute__((address_space(3))) void*)(ldst), 16, 0, 0)

// C[m][n] = sum_k A[m][k] * B[n][k]   (A,B bf16 row-major; C fp32)
// 128x128 tile, BK=64, 4 waves (2x2), each wave 64x64 via 4x4 mfma 16x16x32.
// 16B-block XOR swizzle: LDS slot (row, cb) holds global block (row, cb^(row&7))
// -> ds_read_b128 fragment reads are 2-way-bank (free); staging picks the
// permuted global source per lane (LDS dst of global_load_lds is fixed).
__global__ __launch_bounds__(256, 3)
void gemm_bt_kernel(const __hip_bfloat16* __restrict__ A,
                    const __hip_bfloat16* __restrict__ B,
                    float* __restrict__ C) {
    __shared__ __align__(16) __hip_bfloat16 sA[BM * BK];
    __shared__ __align__(16) __hip_bfloat16 sB[BN * BK];
    const int tid = threadIdx.x;
    const int wave = tid >> 6;
    const int lane = tid & 63;
    const int q = lane >> 4;
    const int t = lane & 15;
    const int wm = wave >> 1;
    const int wn = wave & 1;
    const int bm0 = blockIdx.y * BM;
    const int bn0 = blockIdx.x * BN;

    floatx4 acc[4][4] = {};

    // staging source pointers: inst i covers tile rows i*32..i*32+31
    const __hip_bfloat16* ga[4];
    const __hip_bfloat16* gb[4];
#pragma unroll
    for (int i = 0; i < 4; i++) {
        int rt = i * 32 + (tid >> 3);
        int cb = (tid & 7) ^ (rt & 7);
        ga[i] = A + (size_t)(bm0 + rt) * K_DIM + cb * 8;
        gb[i] = B + (size_t)(bn0 + rt) * K_DIM + cb * 8;
    }

    for (int k0 = 0; k0 < K_DIM; k0 += BK) {
#pragma unroll
        for (int i = 0; i < 4; i++) {
            GL2LDS(ga[i] + k0, (char*)sA + (i * 256 + wave * 64) * 16);
            GL2LDS(gb[i] + k0, (char*)sB + (i * 256 + wave * 64) * 16);
        }
        __syncthreads();
#pragma unroll
        for (int ks = 0; ks < BK; ks += 32) {
            short8 af[4], bfr[4];
#pragma unroll
            for (int mi = 0; mi < 4; mi++) {
                int row = wm * 64 + mi * 16 + t;
                int cb = (ks >> 3) + q;
                af[mi] = *(const short8*)&sA[row * 64 + ((cb ^ (row & 7)) << 3)];
            }
#pragma unroll
            for (int ni = 0; ni < 4; ni++) {
                int row = wn * 64 + ni * 16 + t;
                int cb = (ks >> 3) + q;
                bfr[ni] = *(const short8*)&sB[row * 64 + ((cb ^ (row & 7)) << 3)];
            }
#pragma unroll
            for (int mi = 0; mi < 4; mi++)
#pragma unroll
                for (int ni = 0; ni < 4; ni++)
                    acc[mi][ni] = __builtin_amdgcn_mfma_f32_16x16x32_bf16(
                        af[mi], bfr[ni], acc[mi][ni], 0, 0, 0);
        }
        __syncthreads();
    }

    // epilogue: C/D layout col=lane&15, row=(lane>>4)*4+reg  (m89/m91 verified)
#pragma unroll
    for (int mi = 0; mi < 4; mi++) {
        int row0 = bm0 + wm * 64 + mi * 16 + q * 4;
#pragma unroll
        for (int ni = 0; ni < 4; ni++) {
            int col = bn0 + wn * 64 + ni * 16 + t;
            float* cp = C + (size_t)row0 * N_DIM + col;
#pragma unroll
            for (int r = 0; r < 4; r++) cp[(size_t)r * N_DIM] = acc[mi][ni][r];
        }
    }
}

extern "C" void kernel_launch(void* const* d_in, const int* in_sizes, int n_in,
                              void* d_out, int out_size, void* d_ws,
                              size_t ws_size, hipStream_t stream) {
    const float* x = (const float*)d_in[0];
    const int* codes = (const int*)d_in[1];
    const float* scales = (const float*)d_in[2];
    const float* loraA = (const float*)d_in[3];
    const float* loraB = (const float*)d_in[4];
    float* out = (float*)d_out;

    char* ws = (char*)d_ws;
    __hip_bfloat16* xb = (__hip_bfloat16*)ws;                    // 64 MiB
    __hip_bfloat16* Wb = (__hip_bfloat16*)(ws + 67108864);       // 32 MiB
    float* laT = (float*)(ws + 67108864 + 33554432);             // 256 KiB

    transpose_la_kernel<<<dim3(65536 / 256), dim3(256), 0, stream>>>(loraA, laT);
    dequant_lora_kernel<<<dim3((N_DIM * (K_DIM / 8)) / 256), dim3(256), 0,
                          stream>>>(codes, scales, laT, loraB, (short8*)Wb);
    cast_x_kernel<<<dim3((M_DIM * (K_DIM / 8)) / 256), dim3(256), 0, stream>>>(
        x, (short8*)xb);
    gemm_bt_kernel<<<dim3(N_DIM / BN, M_DIM / BM), dim3(256), 0, stream>>>(
        xb, Wb, out);
}

// Round 2
// 514.878 us; speedup vs baseline: 1.2896x; 1.2896x over previous
//
#include <hip/hip_runtime.h>
#include <hip/hip_bf16.h>

typedef __attribute__((ext_vector_type(8))) short short8;
typedef __attribute__((ext_vector_type(4))) short short4v;
typedef __attribute__((ext_vector_type(4))) float floatx4;

#define M_DIM 8192
#define N_DIM 4096
#define K_DIM 4096
#define BM 128
#define BN 128
#define BK 64

__device__ __constant__ float NF4_TAB[16] = {
    -1.0f, -0.6961928009986877f, -0.5250730514526367f, -0.39491748809814453f,
    -0.28444138169288635f, -0.18477343022823334f, -0.09105003625154495f, 0.0f,
    0.07958029955625534f, 0.16093020141124725f, 0.24611230194568634f,
    0.33791524171829224f, 0.44070982933044434f, 0.5626170039176941f,
    0.7229568362236023f, 1.0f};

// W_eff[n][k] = NF4[code]*scale + 2*sum_r loraB[n][r]*loraA[r][k], as bf16.
// Each thread owns 4 consecutive k (A frag in 16 float4 regs, coalesced loads),
// loops 16 n-rows (n wave-uniform -> loraB row becomes scalar loads).
__global__ __launch_bounds__(256)
void dequant_lora_kernel(const int* __restrict__ codes,
                         const float* __restrict__ scales,
                         const float* __restrict__ la,
                         const float* __restrict__ lb,
                         short4v* __restrict__ W) {
    __shared__ float tab[16];
    if (threadIdx.x < 16) tab[threadIdx.x] = NF4_TAB[threadIdx.x];
    __syncthreads();

    const int kb = blockIdx.x & 3;                 // 4 k-blocks of 1024
    const int n0 = (blockIdx.x >> 2) << 4;         // 16 n-rows per block
    const int k0 = kb * 1024 + threadIdx.x * 4;

    float4 a[16];
#pragma unroll
    for (int r = 0; r < 16; r++)
        a[r] = *(const float4*)(la + (size_t)r * K_DIM + k0);

#pragma unroll 4
    for (int i = 0; i < 16; i++) {
        const int n = n0 + i;
        int4 c = *(const int4*)(codes + (size_t)n * K_DIM + k0);
        float s = scales[(n << 6) + (k0 >> 6)];
        const float* bp = lb + (n << 4);           // wave-uniform -> s_load
        float acc0 = 0.f, acc1 = 0.f, acc2 = 0.f, acc3 = 0.f;
#pragma unroll
        for (int r = 0; r < 16; r++) {
            float br = bp[r];
            acc0 += br * a[r].x;
            acc1 += br * a[r].y;
            acc2 += br * a[r].z;
            acc3 += br * a[r].w;
        }
        union { short4v v; __hip_bfloat16 h[4]; } u;
        u.h[0] = __float2bfloat16(tab[c.x] * s + 2.0f * acc0);
        u.h[1] = __float2bfloat16(tab[c.y] * s + 2.0f * acc1);
        u.h[2] = __float2bfloat16(tab[c.z] * s + 2.0f * acc2);
        u.h[3] = __float2bfloat16(tab[c.w] * s + 2.0f * acc3);
        W[((size_t)n * K_DIM + k0) >> 2] = u.v;
    }
}

// fp32 -> bf16 cast, 8 elements per thread
__global__ void cast_x_kernel(const float* __restrict__ x,
                              short8* __restrict__ xb) {
    int g = blockIdx.x * blockDim.x + threadIdx.x;
    const float4* xp = (const float4*)(x + (size_t)g * 8);
    float4 v0 = xp[0], v1 = xp[1];
    union { short8 v; __hip_bfloat16 h[8]; } u;
    u.h[0] = __float2bfloat16(v0.x);
    u.h[1] = __float2bfloat16(v0.y);
    u.h[2] = __float2bfloat16(v0.z);
    u.h[3] = __float2bfloat16(v0.w);
    u.h[4] = __float2bfloat16(v1.x);
    u.h[5] = __float2bfloat16(v1.y);
    u.h[6] = __float2bfloat16(v1.z);
    u.h[7] = __float2bfloat16(v1.w);
    xb[g] = u.v;
}

#define GL2LDS(gsrc, ldst)                                                   \
    __builtin_amdgcn_global_load_lds(                                        \
        (const __attribute__((address_space(1))) void*)(gsrc),               \
        (__attribute__((address_space(3))) void*)(ldst), 16, 0, 0)

// C[m][n] = sum_k A[m][k] * B[n][k]   (A,B bf16 row-major; C fp32)
// 128x128 tile, BK=64, 4 waves (2x2), each wave 64x64 via 4x4 mfma 16x16x32.
// 16B-block XOR swizzle (applied on global source addrs; LDS dst of
// global_load_lds is fixed base+lane*16) -> ds_read_b128 2-way-bank (free).
__global__ __launch_bounds__(256, 3)
void gemm_bt_kernel(const __hip_bfloat16* __restrict__ A,
                    const __hip_bfloat16* __restrict__ B,
                    float* __restrict__ C) {
    __shared__ __align__(16) __hip_bfloat16 sA[BM * BK];
    __shared__ __align__(16) __hip_bfloat16 sB[BN * BK];
    const int tid = threadIdx.x;
    const int wave = tid >> 6;
    const int lane = tid & 63;
    const int q = lane >> 4;
    const int t = lane & 15;
    const int wm = wave >> 1;
    const int wn = wave & 1;
    const int bm0 = blockIdx.y * BM;
    const int bn0 = blockIdx.x * BN;

    floatx4 acc[4][4] = {};

    const __hip_bfloat16* ga[4];
    const __hip_bfloat16* gb[4];
#pragma unroll
    for (int i = 0; i < 4; i++) {
        int rt = i * 32 + (tid >> 3);
        int cb = (tid & 7) ^ (rt & 7);
        ga[i] = A + (size_t)(bm0 + rt) * K_DIM + cb * 8;
        gb[i] = B + (size_t)(bn0 + rt) * K_DIM + cb * 8;
    }

    for (int k0 = 0; k0 < K_DIM; k0 += BK) {
#pragma unroll
        for (int i = 0; i < 4; i++) {
            GL2LDS(ga[i] + k0, (char*)sA + (i * 256 + wave * 64) * 16);
            GL2LDS(gb[i] + k0, (char*)sB + (i * 256 + wave * 64) * 16);
        }
        __syncthreads();
#pragma unroll
        for (int ks = 0; ks < BK; ks += 32) {
            short8 af[4], bfr[4];
#pragma unroll
            for (int mi = 0; mi < 4; mi++) {
                int row = wm * 64 + mi * 16 + t;
                int cb = (ks >> 3) + q;
                af[mi] = *(const short8*)&sA[row * 64 + ((cb ^ (row & 7)) << 3)];
            }
#pragma unroll
            for (int ni = 0; ni < 4; ni++) {
                int row = wn * 64 + ni * 16 + t;
                int cb = (ks >> 3) + q;
                bfr[ni] = *(const short8*)&sB[row * 64 + ((cb ^ (row & 7)) << 3)];
            }
#pragma unroll
            for (int mi = 0; mi < 4; mi++)
#pragma unroll
                for (int ni = 0; ni < 4; ni++)
                    acc[mi][ni] = __builtin_amdgcn_mfma_f32_16x16x32_bf16(
                        af[mi], bfr[ni], acc[mi][ni], 0, 0, 0);
        }
        __syncthreads();
    }

    // C/D layout col=lane&15, row=(lane>>4)*4+reg  (m89/m91 verified)
#pragma unroll
    for (int mi = 0; mi < 4; mi++) {
        int row0 = bm0 + wm * 64 + mi * 16 + q * 4;
#pragma unroll
        for (int ni = 0; ni < 4; ni++) {
            int col = bn0 + wn * 64 + ni * 16 + t;
            float* cp = C + (size_t)row0 * N_DIM + col;
#pragma unroll
            for (int r = 0; r < 4; r++) cp[(size_t)r * N_DIM] = acc[mi][ni][r];
        }
    }
}

extern "C" void kernel_launch(void* const* d_in, const int* in_sizes, int n_in,
                              void* d_out, int out_size, void* d_ws,
                              size_t ws_size, hipStream_t stream) {
    const float* x = (const float*)d_in[0];
    const int* codes = (const int*)d_in[1];
    const float* scales = (const float*)d_in[2];
    const float* loraA = (const float*)d_in[3];
    const float* loraB = (const float*)d_in[4];
    float* out = (float*)d_out;

    char* ws = (char*)d_ws;
    __hip_bfloat16* xb = (__hip_bfloat16*)ws;                    // 64 MiB
    __hip_bfloat16* Wb = (__hip_bfloat16*)(ws + 67108864);       // 32 MiB

    dequant_lora_kernel<<<dim3(4 * (N_DIM / 16)), dim3(256), 0, stream>>>(
        codes, scales, loraA, loraB, (short4v*)Wb);
    cast_x_kernel<<<dim3((M_DIM * (K_DIM / 8)) / 256), dim3(256), 0, stream>>>(
        x, (short8*)xb);
    gemm_bt_kernel<<<dim3(N_DIM / BN, M_DIM / BM), dim3(256), 0, stream>>>(
        xb, Wb, out);
}